// Round 6
// baseline (332.599 us; speedup 1.0000x reference)
//
#include <hip/hip_runtime.h>
#include <stdint.h>

typedef unsigned short u16;
typedef __bf16 bf16x8 __attribute__((ext_vector_type(8)));
typedef float f32x4 __attribute__((ext_vector_type(4)));
typedef float f32x16 __attribute__((ext_vector_type(16)));
typedef unsigned int u32;

// ---------------------------------------------------------------------------
// Weight "A-image" (u16 elems), 32x32x16-MFMA A-frag native granules:
//   elem[((koct*R + row)*8) + (k&7)],  koct = k>>3, R = rows.
//   L0    : kocts 0..13 (K=112: 96 enc + bias@96 + pad), R=128 -> 14336 elems
//   Hidden: kocts 0..29 (K=240: 128 hid + 96 enc + bias@224 + pad), R=128 -> 30720
//   Out   : kocts 0..29, R=32 (4 real rows) -> 7680
// ---------------------------------------------------------------------------
#define IMG_H(l) (14336 + ((l)-1) * 30720)
#define IMG_OUT 229376
#define IMG_TOTAL 237056

// hidden-feature k-position -> producing layer's C/D feature index.
__device__ inline int fmap(int k) {
    int s = k >> 4, h = (k >> 3) & 1, j = k & 7;
    return 32 * (s >> 1) + 16 * (s & 1) + 8 * (j >> 2) + 4 * h + (j & 3);
}
__device__ inline u16 b16rne(float v) {
    u32 u = __builtin_bit_cast(u32, v);
    u += 0x7FFFu + ((u >> 16) & 1u);
    return (u16)(u >> 16);
}

// ---------------------------------------------------------------------------
// Prep kernel: build bf16 A-image (fmap-permuted hidden cols, identity enc
// cols, bias folded at k=96/224, zero padding).
// ---------------------------------------------------------------------------
__global__ void nf_prep(const float* __restrict__ W0, const float* __restrict__ b0,
                        const float* __restrict__ Wh, const float* __restrict__ bh,
                        const float* __restrict__ Wl, const float* __restrict__ bl,
                        u16* __restrict__ img) {
    int idx = blockIdx.x * 256 + threadIdx.x;
    if (idx >= IMG_TOTAL) return;
    float v;
    if (idx < 14336) {                                    // layer 0
        int gg = idx >> 3, j = idx & 7;
        int koct = gg >> 7, i = gg & 127, k = koct * 8 + j;
        v = (k < 96) ? W0[k * 128 + i] : (k == 96) ? b0[i] : 0.f;
    } else if (idx < IMG_OUT) {                           // hidden 1..7
        int r = idx - 14336, l = r / 30720, rr = r % 30720;
        int gg = rr >> 3, j = rr & 7;
        int koct = gg >> 7, i = gg & 127, k = koct * 8 + j;
        const float* W = Wh + l * 224 * 128;
        v = (k < 128) ? W[fmap(k) * 128 + i]
          : (k < 224) ? W[k * 128 + i]
          : (k == 224) ? bh[l * 128 + i] : 0.f;
    } else {                                              // output layer
        int r = idx - IMG_OUT;
        int gg = r >> 3, j = r & 7;
        int koct = gg >> 5, i = gg & 31, k = koct * 8 + j;
        v = 0.f;
        if (i < 4)
            v = (k < 128) ? Wl[fmap(k) * 4 + i]
              : (k < 224) ? Wl[k * 4 + i]
              : (k == 224) ? bl[i] : 0.f;
    }
    img[idx] = b16rne(v);
}

// ---------------------------------------------------------------------------
// Main kernel helpers
// ---------------------------------------------------------------------------
__device__ inline f32x16 MF32(bf16x8 a, bf16x8 b, f32x16 c) {
    return __builtin_amdgcn_mfma_f32_32x32x16_bf16(a, b, c, 0, 0, 0);
}
__device__ inline bf16x8 fr4(const u32 (&p)[4]) {
    union { u32 u[4]; bf16x8 v; } x;
    x.u[0] = p[0]; x.u[1] = p[1]; x.u[2] = p[2]; x.u[3] = p[3];
    return x.v;
}
__device__ inline bf16x8 frCB(u32 c0) {
    union { u32 u[4]; bf16x8 v; } x;
    x.u[0] = c0; x.u[1] = 0; x.u[2] = 0; x.u[3] = 0;
    return x.v;
}
__device__ inline bf16x8 ldA(const u16* base, int gi) {   // ds_read_b128
    union { uint4 q; bf16x8 v; } x;
    x.q = *(const uint4*)(base + (gi << 3));
    return x.v;
}
__device__ inline u32 pkbf(float a, float b) {            // a->low, b->high
    u32 ua = __builtin_bit_cast(u32, a) + 0x8000u;
    u32 ub = __builtin_bit_cast(u32, b) + 0x8000u;
    return __builtin_amdgcn_perm(ub, ua, 0x07060302u);
}
// async global->LDS stage, 16B/lane, 1KB chunks round-robined over 2 waves
__device__ inline void stageA(const u16* gsrc, u16* ldst, int bytes, int wave, int lane) {
    const char* gs = (const char*)gsrc + lane * 16;
    char* ls = (char*)ldst;
    for (int c = wave * 1024; c < bytes; c += 2048)
        __builtin_amdgcn_global_load_lds(
            (const __attribute__((address_space(1))) void*)(gs + c),
            (__attribute__((address_space(3))) void*)(ls + c), 16, 0, 0);
}
// Zero accumulators in-place (v_accvgpr_write).  DO NOT replace with a
// persistent f32x16 zero operand: that locks 16 VGPRs for the whole kernel
// and pushes the (exactly full) 256-reg unified budget into in-loop scratch
// spills — R4 measured 305 us with 80 MB of spill writes from exactly that.
__device__ inline void zeroacc(f32x16 (&acc)[4][2]) {
#pragma unroll
    for (int t = 0; t < 4; t++)
#pragma unroll
        for (int n = 0; n < 2; n++)
#pragma unroll
            for (int r = 0; r < 16; r++) acc[t][n][r] = 0.f;
}
// ReLU + pack accumulators into next-layer B fragments (in-register handoff)
__device__ inline void buildH(const f32x16 (&acc)[4][2], u32 (&H)[2][8][4]) {
#pragma unroll
    for (int n = 0; n < 2; n++)
#pragma unroll
        for (int s = 0; s < 8; s++) {
            const int t = s >> 1, rb = (s & 1) * 8;
#pragma unroll
            for (int q = 0; q < 4; q++)
                H[n][s][q] = pkbf(fmaxf(acc[t][n][rb + 2 * q], 0.f),
                                  fmaxf(acc[t][n][rb + 2 * q + 1], 0.f));
        }
}
// chunk: 4 ksteps from H fragments H[sb..sb+3]
__device__ inline void cH4(const u16* A, int sb, int h, int m32,
                           f32x16 (&acc)[4][2], const u32 (&H)[2][8][4]) {
#pragma unroll
    for (int sl = 0; sl < 4; sl++) {
        bf16x8 B0 = fr4(H[0][sb + sl]), B1 = fr4(H[1][sb + sl]);
#pragma unroll
        for (int t = 0; t < 4; t++) {
            bf16x8 a = ldA(A, (2 * sl + h) * 128 + t * 32 + m32);
            acc[t][0] = MF32(a, B0, acc[t][0]);
            acc[t][1] = MF32(a, B1, acc[t][1]);
        }
    }
}
// chunk: 4 ksteps from encoding fragments (c0 sin, c0 cos, c1 sin, c1 cos)
__device__ inline void cE4(const u16* A, int h, int m32, f32x16 (&acc)[4][2],
                           const u32 (&E)[2][3][2][4]) {
#pragma unroll
    for (int sl = 0; sl < 4; sl++) {
        bf16x8 B0 = fr4(E[0][sl >> 1][sl & 1]), B1 = fr4(E[1][sl >> 1][sl & 1]);
#pragma unroll
        for (int t = 0; t < 4; t++) {
            bf16x8 a = ldA(A, (2 * sl + h) * 128 + t * 32 + m32);
            acc[t][0] = MF32(a, B0, acc[t][0]);
            acc[t][1] = MF32(a, B1, acc[t][1]);
        }
    }
}
// chunk: 3 ksteps (enc c2 sin, c2 cos, bias), always accumulating
__device__ inline void cTail(const u16* A, int h, int m32, f32x16 (&acc)[4][2],
                             const u32 (&E)[2][3][2][4], u32 CB0) {
#pragma unroll
    for (int sl = 0; sl < 3; sl++) {
        bf16x8 B0, B1;
        if (sl < 2) { B0 = fr4(E[0][2][sl]); B1 = fr4(E[1][2][sl]); }
        else        { B0 = frCB(CB0); B1 = B0; }
#pragma unroll
        for (int t = 0; t < 4; t++) {
            bf16x8 a = ldA(A, (2 * sl + h) * 128 + t * 32 + m32);
            acc[t][0] = MF32(a, B0, acc[t][0]);
            acc[t][1] = MF32(a, B1, acc[t][1]);
        }
    }
}

// ---------------------------------------------------------------------------
// Main fused-MLP kernel.  Block = 128 threads = 2 waves, 128 points/block.
// Wave: 64 points (2 n-tiles of 32), all 128 features (4 m-tiles of 32).
// 32x32x16 MFMA; activations + encoding fragments live in registers;
// weights streamed through 2 x 16KB LDS slabs (quarter-layer chunks, one
// barrier per chunk).  2-wave barrier domains: 4 independent blocks/CU at
// the VGPR-capped 8 waves/CU, so one block's barrier drain hides under
// another's MFMA.  Register budget is EXACTLY full (E 48 + H 64 + temps in
// 128 VGPR; acc 128 AGPR) — see zeroacc note; launch_bounds must stay (128,2).
// ---------------------------------------------------------------------------
__global__ __launch_bounds__(128, 2) void nf_main(const float* __restrict__ qp,
                                                  const u16* __restrict__ img,
                                                  float* __restrict__ out) {
    __shared__ alignas(16) u16 lds[2][8192];   // 2 x 16KB slabs
    const int tid = threadIdx.x, wave = tid >> 6, lane = tid & 63;
    const int m32 = lane & 31, h = lane >> 5;
    const int pbase = blockIdx.x * 128 + wave * 64;

    stageA(img, &lds[0][0], 16384, wave, lane);            // L0 c0: kocts 0..7

    // ---- encoding fragments, computed ONCE, kept in registers ----
    u32 E[2][3][2][4];
    const float sc0 = h ? 128.0f : 0.5f;                   // 2^(8h-1) revolutions
#pragma unroll
    for (int n = 0; n < 2; n++)
#pragma unroll
        for (int c = 0; c < 3; c++) {
            float r = qp[(pbase + n * 32 + m32) * 3 + c] * sc0;
            float sn[8], cs[8];
#pragma unroll
            for (int t = 0; t < 8; t++) {
                float fr = __builtin_amdgcn_fractf(r);
                sn[t] = __builtin_amdgcn_sinf(fr);
                cs[t] = __builtin_amdgcn_cosf(fr);
                r = r * 2.0f;
            }
#pragma unroll
            for (int q = 0; q < 4; q++) {
                E[n][c][0][q] = pkbf(sn[2 * q], sn[2 * q + 1]);
                E[n][c][1][q] = pkbf(cs[2 * q], cs[2 * q + 1]);
            }
        }
    const u32 CB0 = (h == 0) ? 0x00003F80u : 0u;           // bf16(1.0) at j=0,h=0

    f32x16 acc[4][2];
    u32 H[2][8][4];
    zeroacc(acc);

    __syncthreads();                                       // L0 c0 ready
    stageA(img + 8192, &lds[1][0], 12288, wave, lane);     // L0 c1: kocts 8..13
    cE4(&lds[0][0], h, m32, acc, E);                       // L0 ksteps 0..3
    __syncthreads();                                       // L0 c1 ready, slab0 free
    stageA(img + IMG_H(1), &lds[0][0], 16384, wave, lane); // H1 c0
    cTail(&lds[1][0], h, m32, acc, E, CB0);                // L0 ksteps 4..6
    buildH(acc, H);
    __syncthreads();                                       // H1 c0 ready, slab1 free

#pragma unroll 1
    for (int l = 1; l < 8; l++) {
        const int base = IMG_H(l);
        stageA(img + base + 8192, &lds[1][0], 16384, wave, lane);    // c1
        zeroacc(acc);
        cH4(&lds[0][0], 0, h, m32, acc, H);                          // ksteps 0..3
        __syncthreads();
        stageA(img + base + 16384, &lds[0][0], 16384, wave, lane);   // c2
        cH4(&lds[1][0], 4, h, m32, acc, H);                          // ksteps 4..7
        __syncthreads();
        stageA(img + base + 24576, &lds[1][0], 12288, wave, lane);   // c3
        cE4(&lds[0][0], h, m32, acc, E);                             // ksteps 8..11
        __syncthreads();
        const u16* nsrc = (l < 7) ? (img + IMG_H(l + 1)) : (img + IMG_OUT);
        stageA(nsrc, &lds[0][0], (l < 7) ? 16384 : 15360, wave, lane);
        cTail(&lds[1][0], h, m32, acc, E, CB0);                      // ksteps 12..14
        buildH(acc, H);
        __syncthreads();
    }

    // ---- output layer: one 32-row m-tile (rows 0..3 real), K=240, slab 0 ----
    f32x16 o0, o1;
#pragma unroll
    for (int r = 0; r < 16; r++) { o0[r] = 0.f; o1[r] = 0.f; }
#pragma unroll
    for (int s = 0; s < 15; s++) {
        bf16x8 B0, B1;
        if (s < 8)       { B0 = fr4(H[0][s]); B1 = fr4(H[1][s]); }
        else if (s < 14) { B0 = fr4(E[0][(s - 8) >> 1][(s - 8) & 1]);
                           B1 = fr4(E[1][(s - 8) >> 1][(s - 8) & 1]); }
        else             { B0 = frCB(CB0); B1 = B0; }
        bf16x8 a = ldA(&lds[0][0], (2 * s + h) * 32 + m32);
        o0 = MF32(a, B0, o0);
        o1 = MF32(a, B1, o1);
    }
    if (h == 0) {   // rows 0..3 live in regs 0..3 of the h=0 half
        f32x4 w0 = {o0[0], o0[1], o0[2], o0[3]};
        f32x4 w1 = {o1[0], o1[1], o1[2], o1[3]};
        *(f32x4*)(out + 4 * (pbase + m32)) = w0;
        *(f32x4*)(out + 4 * (pbase + 32 + m32)) = w1;
    }
}

// ---------------------------------------------------------------------------
extern "C" void kernel_launch(void* const* d_in, const int* in_sizes, int n_in,
                              void* d_out, int out_size, void* d_ws, size_t ws_size,
                              hipStream_t stream) {
    const float* qp = (const float*)d_in[0];
    const float* W0 = (const float*)d_in[1];
    const float* b0 = (const float*)d_in[2];
    const float* Wh = (const float*)d_in[3];
    const float* bh = (const float*)d_in[4];
    const float* Wl = (const float*)d_in[5];
    const float* bl = (const float*)d_in[6];
    float* out = (float*)d_out;
    u16* img = (u16*)d_ws;   // 474,112 B needed

    nf_prep<<<926, 256, 0, stream>>>(W0, b0, Wh, bh, Wl, bl, img);
    nf_main<<<4096, 128, 0, stream>>>(qp, img, out);
}

// Round 7
// 311.884 us; speedup vs baseline: 1.0664x; 1.0664x over previous
//
#include <hip/hip_runtime.h>
#include <stdint.h>

typedef unsigned short u16;
typedef __bf16 bf16x8 __attribute__((ext_vector_type(8)));
typedef float f32x4 __attribute__((ext_vector_type(4)));
typedef float f32x16 __attribute__((ext_vector_type(16)));
typedef unsigned int u32;

// ---------------------------------------------------------------------------
// Weight "A-image" (u16 elems), 32x32x16-MFMA A-frag native granules:
//   elem[((koct*R + row)*8) + (k&7)],  koct = k>>3, R = rows.
//   L0    : kocts 0..13 (K=112: 96 enc + bias@96 + pad), R=128 -> 14336 elems
//   Hidden: kocts 0..29 (K=240: 128 hid + 96 enc + bias@224 + pad), R=128 -> 30720
//   Out   : kocts 0..29, R=32 (4 real rows) -> 7680
// ---------------------------------------------------------------------------
#define IMG_H(l) (14336 + ((l)-1) * 30720)
#define IMG_OUT 229376
#define IMG_TOTAL 237056

// hidden-feature k-position -> producing layer's C/D feature index.
// kstep s covers features 32*(s>>1)+16*(s&1) .. +15  => s=0..3 <-> feats 0..63
__device__ inline int fmap(int k) {
    int s = k >> 4, h = (k >> 3) & 1, j = k & 7;
    return 32 * (s >> 1) + 16 * (s & 1) + 8 * (j >> 2) + 4 * h + (j & 3);
}
__device__ inline u16 b16rne(float v) {
    u32 u = __builtin_bit_cast(u32, v);
    u += 0x7FFFu + ((u >> 16) & 1u);
    return (u16)(u >> 16);
}

// ---------------------------------------------------------------------------
// Prep kernel (unchanged, verified): bf16 A-image, fmap-permuted hidden cols,
// identity enc cols, bias folded at k=96/224, zero padding.
// ---------------------------------------------------------------------------
__global__ void nf_prep(const float* __restrict__ W0, const float* __restrict__ b0,
                        const float* __restrict__ Wh, const float* __restrict__ bh,
                        const float* __restrict__ Wl, const float* __restrict__ bl,
                        u16* __restrict__ img) {
    int idx = blockIdx.x * 256 + threadIdx.x;
    if (idx >= IMG_TOTAL) return;
    float v;
    if (idx < 14336) {
        int gg = idx >> 3, j = idx & 7;
        int koct = gg >> 7, i = gg & 127, k = koct * 8 + j;
        v = (k < 96) ? W0[k * 128 + i] : (k == 96) ? b0[i] : 0.f;
    } else if (idx < IMG_OUT) {
        int r = idx - 14336, l = r / 30720, rr = r % 30720;
        int gg = rr >> 3, j = rr & 7;
        int koct = gg >> 7, i = gg & 127, k = koct * 8 + j;
        const float* W = Wh + l * 224 * 128;
        v = (k < 128) ? W[fmap(k) * 128 + i]
          : (k < 224) ? W[k * 128 + i]
          : (k == 224) ? bh[l * 128 + i] : 0.f;
    } else {
        int r = idx - IMG_OUT;
        int gg = r >> 3, j = r & 7;
        int koct = gg >> 5, i = gg & 31, k = koct * 8 + j;
        v = 0.f;
        if (i < 4)
            v = (k < 128) ? Wl[fmap(k) * 4 + i]
              : (k < 224) ? Wl[k * 4 + i]
              : (k == 224) ? bl[i] : 0.f;
    }
    img[idx] = b16rne(v);
}

// ---------------------------------------------------------------------------
// Main kernel helpers.  RULE (learned R4/R5): every index into a register
// array (H, E, acc) must be a compile-time constant — runtime indices demote
// the array to scratch (R4/R5: 80 MB of spill stores, +90 us).  Hence the
// template parameters below.
// ---------------------------------------------------------------------------
__device__ inline f32x16 MF32(bf16x8 a, bf16x8 b, f32x16 c) {
    return __builtin_amdgcn_mfma_f32_32x32x16_bf16(a, b, c, 0, 0, 0);
}
__device__ inline bf16x8 fr4(const u32 (&p)[4]) {
    union { u32 u[4]; bf16x8 v; } x;
    x.u[0] = p[0]; x.u[1] = p[1]; x.u[2] = p[2]; x.u[3] = p[3];
    return x.v;
}
__device__ inline bf16x8 frCB(u32 c0) {
    union { u32 u[4]; bf16x8 v; } x;
    x.u[0] = c0; x.u[1] = 0; x.u[2] = 0; x.u[3] = 0;
    return x.v;
}
__device__ inline bf16x8 ldA(const u16* base, int gi) {   // ds_read_b128
    union { uint4 q; bf16x8 v; } x;
    x.q = *(const uint4*)(base + (gi << 3));
    return x.v;
}
__device__ inline u32 pkbf(float a, float b) {            // a->low, b->high
    u32 ua = __builtin_bit_cast(u32, a) + 0x8000u;
    u32 ub = __builtin_bit_cast(u32, b) + 0x8000u;
    return __builtin_amdgcn_perm(ub, ua, 0x07060302u);
}
// async global->LDS stage, 16B/lane, 1KB chunks round-robined over 4 waves
__device__ inline void stageA(const u16* gsrc, u16* ldst, int bytes, int wave, int lane) {
    const char* gs = (const char*)gsrc + lane * 16;
    char* ls = (char*)ldst;
    for (int c = wave * 1024; c < bytes; c += 4096)
        __builtin_amdgcn_global_load_lds(
            (const __attribute__((address_space(1))) void*)(gs + c),
            (__attribute__((address_space(3))) void*)(ls + c), 16, 0, 0);
}
// Zero accumulators in-place.  DO NOT replace with a persistent zero vector
// (R3/R4 lesson: 16 locked VGPRs -> spills).
__device__ inline void zeroacc(f32x16 (&acc)[2][2]) {
#pragma unroll
    for (int t = 0; t < 2; t++)
#pragma unroll
        for (int n = 0; n < 2; n++)
#pragma unroll
            for (int r = 0; r < 16; r++) acc[t][n][r] = 0.f;
}
// ReLU + pack: wave MU builds exactly H-slots 4MU..4MU+3 from its acc half.
template <int MU>
__device__ inline void buildH(const f32x16 (&acc)[2][2], u32 (&H)[2][8][4]) {
#pragma unroll
    for (int n = 0; n < 2; n++)
#pragma unroll
        for (int sl = 0; sl < 4; sl++) {
            const int t = sl >> 1, rb = (sl & 1) * 8;
#pragma unroll
            for (int q = 0; q < 4; q++)
                H[n][4 * MU + sl][q] = pkbf(fmaxf(acc[t][n][rb + 2 * q], 0.f),
                                            fmaxf(acc[t][n][rb + 2 * q + 1], 0.f));
        }
}
// cross-wave H exchange through LDS (frag = 16B/lane, 1KB per (n,sl) slot)
template <int MU>
__device__ inline void exW(u16* ex, int pair, int lane, const u32 (&H)[2][8][4]) {
#pragma unroll
    for (int n = 0; n < 2; n++)
#pragma unroll
        for (int sl = 0; sl < 4; sl++) {
            int fi = pair * 16 + MU * 8 + n * 4 + sl;
            *(uint4*)(ex + (fi * 64 + lane) * 8) = *(const uint4*)&H[n][4 * MU + sl][0];
        }
}
template <int MU>
__device__ inline void exR(const u16* ex, int pair, int lane, u32 (&H)[2][8][4]) {
#pragma unroll
    for (int n = 0; n < 2; n++)
#pragma unroll
        for (int sl = 0; sl < 4; sl++) {
            int fi = pair * 16 + (1 - MU) * 8 + n * 4 + sl;
            *(uint4*)&H[n][4 * (1 - MU) + sl][0] = *(const uint4*)(ex + (fi * 64 + lane) * 8);
        }
}
// chunk: 4 ksteps from H fragments H[SB..SB+3] (SB compile-time!)
template <int SB>
__device__ inline void cH4(const u16* A, int ro, int h, int m32,
                           f32x16 (&acc)[2][2], const u32 (&H)[2][8][4]) {
#pragma unroll
    for (int sl = 0; sl < 4; sl++) {
        bf16x8 B0 = fr4(H[0][SB + sl]), B1 = fr4(H[1][SB + sl]);
#pragma unroll
        for (int t = 0; t < 2; t++) {
            bf16x8 a = ldA(A, (2 * sl + h) * 128 + ro + t * 32 + m32);
            acc[t][0] = MF32(a, B0, acc[t][0]);
            acc[t][1] = MF32(a, B1, acc[t][1]);
        }
    }
}
// chunk: 4 ksteps from encoding fragments (c0 sin, c0 cos, c1 sin, c1 cos)
__device__ inline void cE4(const u16* A, int ro, int h, int m32,
                           f32x16 (&acc)[2][2], const u32 (&E)[2][3][2][4]) {
#pragma unroll
    for (int sl = 0; sl < 4; sl++) {
        bf16x8 B0 = fr4(E[0][sl >> 1][sl & 1]), B1 = fr4(E[1][sl >> 1][sl & 1]);
#pragma unroll
        for (int t = 0; t < 2; t++) {
            bf16x8 a = ldA(A, (2 * sl + h) * 128 + ro + t * 32 + m32);
            acc[t][0] = MF32(a, B0, acc[t][0]);
            acc[t][1] = MF32(a, B1, acc[t][1]);
        }
    }
}
// chunk: 3 ksteps (enc c2 sin, c2 cos, bias)
__device__ inline void cTail(const u16* A, int ro, int h, int m32,
                             f32x16 (&acc)[2][2], const u32 (&E)[2][3][2][4], u32 CB0) {
#pragma unroll
    for (int sl = 0; sl < 3; sl++) {
        bf16x8 B0, B1;
        if (sl < 2) { B0 = fr4(E[0][2][sl]); B1 = fr4(E[1][2][sl]); }
        else        { B0 = frCB(CB0); B1 = B0; }
#pragma unroll
        for (int t = 0; t < 2; t++) {
            bf16x8 a = ldA(A, (2 * sl + h) * 128 + ro + t * 32 + m32);
            acc[t][0] = MF32(a, B0, acc[t][0]);
            acc[t][1] = MF32(a, B1, acc[t][1]);
        }
    }
}
// output layer: wave MU computes its n-tile (n = MU), 15 ksteps, R=32
template <int MU>
__device__ inline void outCompute(const u16* A, int h, int m32,
                                  const u32 (&H)[2][8][4], const u32 (&E)[2][3][2][4],
                                  u32 CB0, float* out, int pbase) {
    f32x16 o;
#pragma unroll
    for (int r = 0; r < 16; r++) o[r] = 0.f;
#pragma unroll
    for (int s = 0; s < 15; s++) {
        bf16x8 B;
        if (s < 8)       B = fr4(H[MU][s]);
        else if (s < 14) B = fr4(E[MU][(s - 8) >> 1][(s - 8) & 1]);
        else             B = frCB(CB0);
        bf16x8 a = ldA(A, (2 * s + h) * 32 + m32);
        o = MF32(a, B, o);
    }
    if (h == 0) {
        f32x4 w = {o[0], o[1], o[2], o[3]};
        *(f32x4*)(out + 4 * (pbase + MU * 32 + m32)) = w;
    }
}

// ---------------------------------------------------------------------------
// Main fused-MLP kernel, m-split edition.
// Block = 256 threads = 4 waves = 2 wave-pairs; pair owns 64 points.
// Each wave: 64 points x 64 FEATURES (m-half mu) -> acc = 2x2 f32x16 = 64 regs
// (vs 128), freeing ~64 VGPRs of headroom for ds_read->MFMA pipelining.
// The sigma permutation splits by construction: kstep s of the next layer
// depends only on t-tile s>>1, so wave mu builds H-slots 4mu..4mu+3 locally
// and swaps the other half with its partner via a 32KB LDS region (16 ds ops
// per wave per layer).  Same k-accumulation order as R2 -> bit-identical out.
// LDS: 2 x 16KB weight slabs + 32KB exchange = 64KB; 2 blocks/CU.
// __launch_bounds__ must stay (256,2): 256-reg/wave budget (R3 spilled at 4).
// ---------------------------------------------------------------------------
__global__ __launch_bounds__(256, 2) void nf_main(const float* __restrict__ qp,
                                                  const u16* __restrict__ img,
                                                  float* __restrict__ out) {
    __shared__ alignas(16) u16 lds[2][8192];   // 2 x 16KB weight slabs
    __shared__ alignas(16) u16 ex[16384];      // 32KB H-exchange
    const int tid = threadIdx.x, wave = tid >> 6, lane = tid & 63;
    const int m32 = lane & 31, h = lane >> 5;
    const int pair = wave >> 1, mu = wave & 1;
    const int ro = mu * 64;                    // row offset of this wave's m-half
    const int pbase = blockIdx.x * 128 + pair * 64;

    stageA(img, &lds[0][0], 16384, wave, lane);            // L0 c0 (ks 0..3)

    // ---- encoding fragments, computed once, kept in registers ----
    u32 E[2][3][2][4];
    const float sc0 = h ? 128.0f : 0.5f;                   // 2^(8h-1) revolutions
#pragma unroll
    for (int n = 0; n < 2; n++)
#pragma unroll
        for (int c = 0; c < 3; c++) {
            float r = qp[(pbase + n * 32 + m32) * 3 + c] * sc0;
            float sn[8], cs[8];
#pragma unroll
            for (int t = 0; t < 8; t++) {
                float fr = __builtin_amdgcn_fractf(r);
                sn[t] = __builtin_amdgcn_sinf(fr);
                cs[t] = __builtin_amdgcn_cosf(fr);
                r = r * 2.0f;
            }
#pragma unroll
            for (int q = 0; q < 4; q++) {
                E[n][c][0][q] = pkbf(sn[2 * q], sn[2 * q + 1]);
                E[n][c][1][q] = pkbf(cs[2 * q], cs[2 * q + 1]);
            }
        }
    const u32 CB0 = (h == 0) ? 0x00003F80u : 0u;           // bf16(1.0) at j=0,h=0

    f32x16 acc[2][2];
    u32 H[2][8][4];
    zeroacc(acc);

    __syncthreads();                                       // L0 c0 ready
    stageA(img + 8192, &lds[1][0], 12288, wave, lane);     // L0 c1 (ks 4..6)
    cE4(&lds[0][0], ro, h, m32, acc, E);                   // L0 ks 0..3
    __syncthreads();                                       // L0 c1 ready
    stageA(img + IMG_H(1), &lds[0][0], 16384, wave, lane); // H1 c0
    cTail(&lds[1][0], ro, h, m32, acc, E, CB0);            // L0 ks 4..6
    if (mu == 0) { buildH<0>(acc, H); exW<0>(ex, pair, lane, H); }
    else         { buildH<1>(acc, H); exW<1>(ex, pair, lane, H); }
    __syncthreads();                                       // H1 c0 + exch ready
    if (mu == 0) exR<0>(ex, pair, lane, H); else exR<1>(ex, pair, lane, H);

#pragma unroll 1
    for (int l = 1; l < 8; l++) {
        const int base = IMG_H(l);
        zeroacc(acc);
        stageA(img + base + 8192, &lds[1][0], 16384, wave, lane);   // c1
        cH4<0>(&lds[0][0], ro, h, m32, acc, H);                     // ks 0..3
        __syncthreads();
        stageA(img + base + 16384, &lds[0][0], 16384, wave, lane);  // c2
        cH4<4>(&lds[1][0], ro, h, m32, acc, H);                     // ks 4..7
        __syncthreads();
        stageA(img + base + 24576, &lds[1][0], 12288, wave, lane);  // c3
        cE4(&lds[0][0], ro, h, m32, acc, E);                        // ks 8..11
        __syncthreads();
        const u16* nsrc = (l < 7) ? (img + IMG_H(l + 1)) : (img + IMG_OUT);
        stageA(nsrc, &lds[0][0], (l < 7) ? 16384 : 15360, wave, lane);
        cTail(&lds[1][0], ro, h, m32, acc, E, CB0);                 // ks 12..14
        if (mu == 0) { buildH<0>(acc, H); exW<0>(ex, pair, lane, H); }
        else         { buildH<1>(acc, H); exW<1>(ex, pair, lane, H); }
        __syncthreads();                                            // next c0 + exch
        if (mu == 0) exR<0>(ex, pair, lane, H); else exR<1>(ex, pair, lane, H);
    }

    // ---- output layer from slab 0 ----
    if (mu == 0) outCompute<0>(&lds[0][0], h, m32, H, E, CB0, out, pbase);
    else         outCompute<1>(&lds[0][0], h, m32, H, E, CB0, out, pbase);
}

// ---------------------------------------------------------------------------
extern "C" void kernel_launch(void* const* d_in, const int* in_sizes, int n_in,
                              void* d_out, int out_size, void* d_ws, size_t ws_size,
                              hipStream_t stream) {
    const float* qp = (const float*)d_in[0];
    const float* W0 = (const float*)d_in[1];
    const float* b0 = (const float*)d_in[2];
    const float* Wh = (const float*)d_in[3];
    const float* bh = (const float*)d_in[4];
    const float* Wl = (const float*)d_in[5];
    const float* bl = (const float*)d_in[6];
    float* out = (float*)d_out;
    u16* img = (u16*)d_ws;   // 474,112 B needed

    nf_prep<<<926, 256, 0, stream>>>(W0, b0, Wh, bh, Wl, bl, img);
    nf_main<<<4096, 256, 0, stream>>>(qp, img, out);
}